// Round 7
// baseline (277.910 us; speedup 1.0000x reference)
//
#include <hip/hip_runtime.h>

// LocalChargeEnergy:
//   lin  = f0@w0 + (f1@w1 + b1) + (f2@w2 + b2)          [n_atoms]
//   e    = (lin * charge)^2 + lin                        [n_atoms]
//   mol  = segment_sum(e, mol_index, n_mol)              [n_mol]
// Outputs concatenated: mol (n_mol floats) then e (n_atoms floats).
//
// Streaming-BW regime: round 5 hit 5.77 TB/s delivered (92% of m13 copy
// ceiling). This round: explicit register double-buffer prefetch of the next
// 4-atom group (12 KB in flight per wave), nt stores (via ext_vector_type --
// __builtin_nontemporal_store rejects HIP_vector_type), balanced quad split.

typedef float f32x4 __attribute__((ext_vector_type(4)));

__global__ void zero_kernel(float* __restrict__ p, int n) {
    int i = blockIdx.x * blockDim.x + threadIdx.x;
    if (i < n) p[i] = 0.0f;
}

__device__ __forceinline__ float dot12(const f32x4 a, const f32x4 b, const f32x4 c,
                                       const f32x4 wa, const f32x4 wb, const f32x4 wc) {
    return a.x * wa.x + a.y * wa.y + a.z * wa.z + a.w * wa.w
         + b.x * wb.x + b.y * wb.y + b.z * wb.z + b.w * wb.w
         + c.x * wc.x + c.y * wc.y + c.z * wc.z + c.w * wc.w;
}

__global__ void __launch_bounds__(256)
charge_energy_kernel(const float* __restrict__ charges,
                     const float* __restrict__ f0,
                     const float* __restrict__ f1,
                     const float* __restrict__ f2,
                     const int*   __restrict__ mol_index,
                     const float* __restrict__ w0,
                     const float* __restrict__ w1,
                     const float* __restrict__ w2,
                     const float* __restrict__ b1p,
                     const float* __restrict__ b2p,
                     float* __restrict__ mol_out,    // [n_mol], pre-zeroed
                     float* __restrict__ atom_out,   // [n_atoms]
                     int n_atoms,
                     int nq_base,                    // quads per wave (floor)
                     int nq_rem,                     // first nq_rem waves get +1
                     int n_waves)
{
    const int lane   = threadIdx.x & 63;
    const int lane32 = lane & 31;
    const long long wid = (long long)blockIdx.x * (blockDim.x >> 6) + (threadIdx.x >> 6);
    if (wid >= n_waves) return;

    // Balanced contiguous quad range [q0, q1) for this wave.
    const long long q0 = wid * (long long)nq_base + (wid < nq_rem ? wid : nq_rem);
    const long long q1 = q0 + nq_base + (wid < nq_rem ? 1 : 0);
    long long a  = q0 * 4;
    const long long aQ = q1 * 4;

    const float bias = b1p[0] + b2p[0];
    const f32x4 w0c = reinterpret_cast<const f32x4*>(w0)[lane32];
    const f32x4 w1c = reinterpret_cast<const f32x4*>(w1)[lane32];
    const f32x4 w2c = reinterpret_cast<const f32x4*>(w2)[lane32];

    const f32x4* p0 = reinterpret_cast<const f32x4*>(f0);
    const f32x4* p1 = reinterpret_cast<const f32x4*>(f1);
    const f32x4* p2 = reinterpret_cast<const f32x4*>(f2);

    int   cur_mol = -1;     // run-length state (meaningful on lane 0 only)
    float cur_sum = 0.0f;

    // Register double-buffer: current 4-atom group + prefetched next group.
    f32x4 ca0, ca1, ca2, cb0, cb1, cb2;
    if (a < aQ) {
        const long long base = a * 32;
        ca0 = __builtin_nontemporal_load(p0 + base + lane);
        ca1 = __builtin_nontemporal_load(p1 + base + lane);
        ca2 = __builtin_nontemporal_load(p2 + base + lane);
        cb0 = __builtin_nontemporal_load(p0 + base + 64 + lane);
        cb1 = __builtin_nontemporal_load(p1 + base + 64 + lane);
        cb2 = __builtin_nontemporal_load(p2 + base + 64 + lane);
    }

    for (; a < aQ; a += 4) {
        // Issue next group's 6 loads before touching current data.
        f32x4 na0, na1, na2, nb0, nb1, nb2;
        const bool has_next = (a + 4 < aQ);
        if (has_next) {
            const long long nb = (a + 4) * 32;
            na0 = __builtin_nontemporal_load(p0 + nb + lane);
            na1 = __builtin_nontemporal_load(p1 + nb + lane);
            na2 = __builtin_nontemporal_load(p2 + nb + lane);
            nb0 = __builtin_nontemporal_load(p0 + nb + 64 + lane);
            nb1 = __builtin_nontemporal_load(p1 + nb + 64 + lane);
            nb2 = __builtin_nontemporal_load(p2 + nb + 64 + lane);
        }

        const float4 cc = *reinterpret_cast<const float4*>(charges + a);
        const int4   mm = *reinterpret_cast<const int4*>(mol_index + a);

        float pA = dot12(ca0, ca1, ca2, w0c, w1c, w2c);
        float pB = dot12(cb0, cb1, cb2, w0c, w1c, w2c);

        // Two independent 5-step reduces (xor masks <32 stay within each half).
        #pragma unroll
        for (int m = 16; m >= 1; m >>= 1) {
            pA += __shfl_xor(pA, m, 64);
            pB += __shfl_xor(pB, m, 64);
        }
        const float s1 = __shfl(pA, 32, 64);   // row a+1 sum
        const float s3 = __shfl(pB, 32, 64);   // row a+3 sum

        if (lane == 0) {
            const float lin0 = pA + bias, lin1 = s1 + bias;
            const float lin2 = pB + bias, lin3 = s3 + bias;
            const float t0 = lin0 * cc.x, t1 = lin1 * cc.y;
            const float t2 = lin2 * cc.z, t3 = lin3 * cc.w;
            const float e0 = t0 * t0 + lin0, e1 = t1 * t1 + lin1;
            const float e2 = t2 * t2 + lin2, e3 = t3 * t3 + lin3;
            f32x4 ev; ev.x = e0; ev.y = e1; ev.z = e2; ev.w = e3;
            __builtin_nontemporal_store(ev, reinterpret_cast<f32x4*>(atom_out + a));

            // Run-length segment accumulation (mol_index sorted).
            const int   ms[4] = {mm.x, mm.y, mm.z, mm.w};
            const float es[4] = {e0, e1, e2, e3};
            #pragma unroll
            for (int k = 0; k < 4; ++k) {
                if (ms[k] != cur_mol) {
                    if (cur_mol >= 0) atomicAdd(&mol_out[cur_mol], cur_sum);
                    cur_mol = ms[k]; cur_sum = es[k];
                } else {
                    cur_sum += es[k];
                }
            }
        }

        if (has_next) {
            ca0 = na0; ca1 = na1; ca2 = na2;
            cb0 = nb0; cb1 = nb1; cb2 = nb2;
        }
    }

    // Scalar remainder atoms (n_atoms % 4), handled by the last wave.
    if (wid == n_waves - 1) {
        for (long long r = aQ > (long long)(n_atoms & ~3LL) ? aQ : (long long)(n_atoms & ~3LL);
             r < n_atoms; ++r) {
            const f32x4 x0 = (p0 + r * 32)[lane32];
            const f32x4 x1 = (p1 + r * 32)[lane32];
            const f32x4 x2 = (p2 + r * 32)[lane32];
            float p = dot12(x0, x1, x2, w0c, w1c, w2c);
            #pragma unroll
            for (int m = 16; m >= 1; m >>= 1) p += __shfl_xor(p, m, 64);
            if (lane == 0) {
                const float lin = p + bias;
                const float t = lin * charges[r];
                const float e = t * t + lin;
                atom_out[r] = e;
                const int mi = mol_index[r];
                if (mi != cur_mol) {
                    if (cur_mol >= 0) atomicAdd(&mol_out[cur_mol], cur_sum);
                    cur_mol = mi; cur_sum = e;
                } else cur_sum += e;
            }
        }
    }

    if (lane == 0 && cur_mol >= 0)
        atomicAdd(&mol_out[cur_mol], cur_sum);
}

extern "C" void kernel_launch(void* const* d_in, const int* in_sizes, int n_in,
                              void* d_out, int out_size, void* d_ws, size_t ws_size,
                              hipStream_t stream) {
    const float* charges   = (const float*)d_in[0];
    const float* f0        = (const float*)d_in[1];
    const float* f1        = (const float*)d_in[2];
    const float* f2        = (const float*)d_in[3];
    const int*   mol_index = (const int*)  d_in[4];
    // d_in[5] = n_molecules (device scalar; derived on host instead)
    const float* w0        = (const float*)d_in[6];
    const float* w1        = (const float*)d_in[7];
    const float* w2        = (const float*)d_in[8];
    const float* b1p       = (const float*)d_in[9];
    const float* b2p       = (const float*)d_in[10];

    const int n_atoms = in_sizes[0];          // charges element count
    const int n_mol   = out_size - n_atoms;   // outputs are [mol | atom]

    float* mol_out  = (float*)d_out;
    float* atom_out = mol_out + n_mol;

    // Zero the molecule accumulators every call (harness never re-poisons).
    {
        int blocks = (n_mol + 255) / 256;
        hipLaunchKernelGGL(zero_kernel, dim3(blocks), dim3(256), 0, stream,
                           mol_out, n_mol);
    }

    // 2048 blocks x 4 waves = 8192 waves = 256CU x 32-wave capacity.
    const int blocks  = 2048;
    const int n_waves = blocks * (256 / 64);
    const int nq      = n_atoms >> 2;         // 4-atom groups
    const int nq_base = nq / n_waves;
    const int nq_rem  = nq % n_waves;

    hipLaunchKernelGGL(charge_energy_kernel, dim3(blocks), dim3(256), 0, stream,
                       charges, f0, f1, f2, mol_index, w0, w1, w2, b1p, b2p,
                       mol_out, atom_out, n_atoms, nq_base, nq_rem, n_waves);
}

// Round 8
// 266.559 us; speedup vs baseline: 1.0426x; 1.0426x over previous
//
#include <hip/hip_runtime.h>

// LocalChargeEnergy:
//   lin  = f0@w0 + (f1@w1 + b1) + (f2@w2 + b2)          [n_atoms]
//   e    = (lin * charge)^2 + lin                        [n_atoms]
//   mol  = segment_sum(e, mol_index, n_mol)              [n_mol]
// Outputs concatenated: mol (n_mol floats) then e (n_atoms floats).
//
// Round 5 (4-atom iter, nt loads): 268 us = 5.77 TB/s = 92% of copy ceiling.
// Round 6 (manual reg dbuf): REGRESSED -- compiler already pipelines.
// This round: flat 8-atom iteration (12 independent nt dwordx4 loads at the
// top, compiler-scheduled), balanced oct split across waves. No manual dbuf.

typedef float f32x4 __attribute__((ext_vector_type(4)));

__global__ void zero_kernel(float* __restrict__ p, int n) {
    int i = blockIdx.x * blockDim.x + threadIdx.x;
    if (i < n) p[i] = 0.0f;
}

__device__ __forceinline__ float dot12(const f32x4 a, const f32x4 b, const f32x4 c,
                                       const f32x4 wa, const f32x4 wb, const f32x4 wc) {
    return a.x * wa.x + a.y * wa.y + a.z * wa.z + a.w * wa.w
         + b.x * wb.x + b.y * wb.y + b.z * wb.z + b.w * wb.w
         + c.x * wc.x + c.y * wc.y + c.z * wc.z + c.w * wc.w;
}

__global__ void __launch_bounds__(256)
charge_energy_kernel(const float* __restrict__ charges,
                     const float* __restrict__ f0,
                     const float* __restrict__ f1,
                     const float* __restrict__ f2,
                     const int*   __restrict__ mol_index,
                     const float* __restrict__ w0,
                     const float* __restrict__ w1,
                     const float* __restrict__ w2,
                     const float* __restrict__ b1p,
                     const float* __restrict__ b2p,
                     float* __restrict__ mol_out,    // [n_mol], pre-zeroed
                     float* __restrict__ atom_out,   // [n_atoms]
                     int n_atoms,
                     int no_base,                    // octs per wave (floor)
                     int no_rem,                     // first no_rem waves get +1
                     int n_waves)
{
    const int lane   = threadIdx.x & 63;
    const int lane32 = lane & 31;
    const long long wid = (long long)blockIdx.x * (blockDim.x >> 6) + (threadIdx.x >> 6);
    if (wid >= n_waves) return;

    // Balanced contiguous oct (8-atom group) range for this wave.
    const long long o0 = wid * (long long)no_base + (wid < no_rem ? wid : no_rem);
    const long long o1 = o0 + no_base + (wid < no_rem ? 1 : 0);
    long long a  = o0 * 8;
    const long long aE = o1 * 8;

    const float bias = b1p[0] + b2p[0];
    const f32x4 w0c = reinterpret_cast<const f32x4*>(w0)[lane32];
    const f32x4 w1c = reinterpret_cast<const f32x4*>(w1)[lane32];
    const f32x4 w2c = reinterpret_cast<const f32x4*>(w2)[lane32];

    const f32x4* p0 = reinterpret_cast<const f32x4*>(f0);
    const f32x4* p1 = reinterpret_cast<const f32x4*>(f1);
    const f32x4* p2 = reinterpret_cast<const f32x4*>(f2);

    int   cur_mol = -1;     // run-length state (meaningful on lane 0 only)
    float cur_sum = 0.0f;

    for (; a < aE; a += 8) {
        const long long base = a * 32;
        // 12 independent 1KB loads (24 KB per wave in flight), issued together.
        const f32x4 xa0 = __builtin_nontemporal_load(p0 + base + lane);        // rows a,a+1
        const f32x4 xa1 = __builtin_nontemporal_load(p1 + base + lane);
        const f32x4 xa2 = __builtin_nontemporal_load(p2 + base + lane);
        const f32x4 xb0 = __builtin_nontemporal_load(p0 + base + 64 + lane);   // a+2,a+3
        const f32x4 xb1 = __builtin_nontemporal_load(p1 + base + 64 + lane);
        const f32x4 xb2 = __builtin_nontemporal_load(p2 + base + 64 + lane);
        const f32x4 xc0 = __builtin_nontemporal_load(p0 + base + 128 + lane);  // a+4,a+5
        const f32x4 xc1 = __builtin_nontemporal_load(p1 + base + 128 + lane);
        const f32x4 xc2 = __builtin_nontemporal_load(p2 + base + 128 + lane);
        const f32x4 xd0 = __builtin_nontemporal_load(p0 + base + 192 + lane);  // a+6,a+7
        const f32x4 xd1 = __builtin_nontemporal_load(p1 + base + 192 + lane);
        const f32x4 xd2 = __builtin_nontemporal_load(p2 + base + 192 + lane);

        const float4 cc0 = *reinterpret_cast<const float4*>(charges + a);
        const float4 cc1 = *reinterpret_cast<const float4*>(charges + a + 4);
        const int4   mm0 = *reinterpret_cast<const int4*>(mol_index + a);
        const int4   mm1 = *reinterpret_cast<const int4*>(mol_index + a + 4);

        float pA = dot12(xa0, xa1, xa2, w0c, w1c, w2c);
        float pB = dot12(xb0, xb1, xb2, w0c, w1c, w2c);
        float pC = dot12(xc0, xc1, xc2, w0c, w1c, w2c);
        float pD = dot12(xd0, xd1, xd2, w0c, w1c, w2c);

        // Four independent 5-step reduces (xor masks <32 stay within halves).
        #pragma unroll
        for (int m = 16; m >= 1; m >>= 1) {
            pA += __shfl_xor(pA, m, 64);
            pB += __shfl_xor(pB, m, 64);
            pC += __shfl_xor(pC, m, 64);
            pD += __shfl_xor(pD, m, 64);
        }
        const float s1 = __shfl(pA, 32, 64);
        const float s3 = __shfl(pB, 32, 64);
        const float s5 = __shfl(pC, 32, 64);
        const float s7 = __shfl(pD, 32, 64);

        if (lane == 0) {
            const float lin0 = pA + bias, lin1 = s1 + bias;
            const float lin2 = pB + bias, lin3 = s3 + bias;
            const float lin4 = pC + bias, lin5 = s5 + bias;
            const float lin6 = pD + bias, lin7 = s7 + bias;
            const float t0 = lin0 * cc0.x, t1 = lin1 * cc0.y;
            const float t2 = lin2 * cc0.z, t3 = lin3 * cc0.w;
            const float t4 = lin4 * cc1.x, t5 = lin5 * cc1.y;
            const float t6 = lin6 * cc1.z, t7 = lin7 * cc1.w;
            const float e0 = t0 * t0 + lin0, e1 = t1 * t1 + lin1;
            const float e2 = t2 * t2 + lin2, e3 = t3 * t3 + lin3;
            const float e4 = t4 * t4 + lin4, e5 = t5 * t5 + lin5;
            const float e6 = t6 * t6 + lin6, e7 = t7 * t7 + lin7;
            f32x4 ev0; ev0.x = e0; ev0.y = e1; ev0.z = e2; ev0.w = e3;
            f32x4 ev1; ev1.x = e4; ev1.y = e5; ev1.z = e6; ev1.w = e7;
            __builtin_nontemporal_store(ev0, reinterpret_cast<f32x4*>(atom_out + a));
            __builtin_nontemporal_store(ev1, reinterpret_cast<f32x4*>(atom_out + a + 4));

            // Run-length segment accumulation (mol_index sorted).
            const int   ms[8] = {mm0.x, mm0.y, mm0.z, mm0.w, mm1.x, mm1.y, mm1.z, mm1.w};
            const float es[8] = {e0, e1, e2, e3, e4, e5, e6, e7};
            #pragma unroll
            for (int k = 0; k < 8; ++k) {
                if (ms[k] != cur_mol) {
                    if (cur_mol >= 0) atomicAdd(&mol_out[cur_mol], cur_sum);
                    cur_mol = ms[k]; cur_sum = es[k];
                } else {
                    cur_sum += es[k];
                }
            }
        }
    }

    // Scalar remainder atoms (n_atoms % 8), handled by the last wave.
    if (wid == n_waves - 1) {
        for (long long r = (long long)(n_atoms & ~7LL); r < n_atoms; ++r) {
            const f32x4 x0 = (p0 + r * 32)[lane32];
            const f32x4 x1 = (p1 + r * 32)[lane32];
            const f32x4 x2 = (p2 + r * 32)[lane32];
            float p = dot12(x0, x1, x2, w0c, w1c, w2c);
            #pragma unroll
            for (int m = 16; m >= 1; m >>= 1) p += __shfl_xor(p, m, 64);
            if (lane == 0) {
                const float lin = p + bias;
                const float t = lin * charges[r];
                const float e = t * t + lin;
                atom_out[r] = e;
                const int mi = mol_index[r];
                if (mi != cur_mol) {
                    if (cur_mol >= 0) atomicAdd(&mol_out[cur_mol], cur_sum);
                    cur_mol = mi; cur_sum = e;
                } else cur_sum += e;
            }
        }
    }

    if (lane == 0 && cur_mol >= 0)
        atomicAdd(&mol_out[cur_mol], cur_sum);
}

extern "C" void kernel_launch(void* const* d_in, const int* in_sizes, int n_in,
                              void* d_out, int out_size, void* d_ws, size_t ws_size,
                              hipStream_t stream) {
    const float* charges   = (const float*)d_in[0];
    const float* f0        = (const float*)d_in[1];
    const float* f1        = (const float*)d_in[2];
    const float* f2        = (const float*)d_in[3];
    const int*   mol_index = (const int*)  d_in[4];
    // d_in[5] = n_molecules (device scalar; derived on host instead)
    const float* w0        = (const float*)d_in[6];
    const float* w1        = (const float*)d_in[7];
    const float* w2        = (const float*)d_in[8];
    const float* b1p       = (const float*)d_in[9];
    const float* b2p       = (const float*)d_in[10];

    const int n_atoms = in_sizes[0];          // charges element count
    const int n_mol   = out_size - n_atoms;   // outputs are [mol | atom]

    float* mol_out  = (float*)d_out;
    float* atom_out = mol_out + n_mol;

    // Zero the molecule accumulators every call (harness never re-poisons).
    {
        int blocks = (n_mol + 255) / 256;
        hipLaunchKernelGGL(zero_kernel, dim3(blocks), dim3(256), 0, stream,
                           mol_out, n_mol);
    }

    // 2048 blocks x 4 waves = 8192 waves = 256CU x 32-wave capacity.
    const int blocks  = 2048;
    const int n_waves = blocks * (256 / 64);
    const int no      = n_atoms >> 3;         // 8-atom groups
    const int no_base = no / n_waves;
    const int no_rem  = no % n_waves;

    hipLaunchKernelGGL(charge_energy_kernel, dim3(blocks), dim3(256), 0, stream,
                       charges, f0, f1, f2, mol_index, w0, w1, w2, b1p, b2p,
                       mol_out, atom_out, n_atoms, no_base, no_rem, n_waves);
}